// Round 19
// baseline (129.942 us; speedup 1.0000x reference)
//
#include <hip/hip_runtime.h>
#include <hip/hip_bf16.h>

typedef __attribute__((ext_vector_type(8))) short bf16x8;
typedef __attribute__((ext_vector_type(4))) short bf16x4;
typedef __attribute__((ext_vector_type(4))) float f32x4;

static __device__ __forceinline__ __hip_bfloat16 f2b(float f) {
    return __float2bfloat16(f);
}
static __device__ __forceinline__ unsigned pack2(float a, float b) {
    unsigned ua = (unsigned)__bfloat16_as_ushort(__float2bfloat16(a));
    unsigned ub = (unsigned)__bfloat16_as_ushort(__float2bfloat16(b));
    return ua | (ub << 16);
}
static __device__ __forceinline__ float exp2fast(float x) {
    return __builtin_amdgcn_exp2f(x);
}

#define QSCALE 0.1803368801111f   // 0.125 * log2(e)

// ---------------------------------------------------------------------------
// Fused prep: blocks [0,2048) convert x f32->bf16; [2048,5120) transpose
// Wqkv -> WqkvT bf16; [5120,6144) transpose Wo -> WoT bf16.
// ---------------------------------------------------------------------------
__global__ __launch_bounds__(256) void k_prep(
    const float* __restrict__ x, __hip_bfloat16* __restrict__ xb,
    const float* __restrict__ Wqkv, __hip_bfloat16* __restrict__ WqkvT,
    const float* __restrict__ Wo, __hip_bfloat16* __restrict__ WoT)
{
    const int bx = blockIdx.x;
    if (bx < 2048) {
        int i = bx * 256 + threadIdx.x;
        const int stride = 2048 * 256;
        for (; i < 1048576; i += stride) {
            float4 v = reinterpret_cast<const float4*>(x)[i];
            __hip_bfloat16* o = xb + 4 * (size_t)i;
            o[0] = f2b(v.x); o[1] = f2b(v.y); o[2] = f2b(v.z); o[3] = f2b(v.w);
        }
        return;
    }
    __shared__ float tile[32][33];
    const float* in;
    __hip_bfloat16* outp;
    int R, Cn, c0, r0;
    if (bx < 5120) {
        const int b = bx - 2048;
        in = Wqkv; outp = WqkvT; R = 1024; Cn = 3072;
        c0 = (b % 96) * 32; r0 = (b / 96) * 32;
    } else {
        const int b = bx - 5120;
        in = Wo; outp = WoT; R = 1024; Cn = 1024;
        c0 = (b & 31) * 32; r0 = (b >> 5) * 32;
    }
    const int tx = threadIdx.x & 31, ty = threadIdx.x >> 5;
#pragma unroll
    for (int i = 0; i < 32; i += 8)
        tile[ty + i][tx] = in[(size_t)(r0 + ty + i) * Cn + c0 + tx];
    __syncthreads();
#pragma unroll
    for (int i = 0; i < 32; i += 8)
        outp[(size_t)(c0 + ty + i) * R + r0 + tx] = f2b(tile[tx][ty + i]);
}

// ---------------------------------------------------------------------------
// GEMM1 qkv: 128x128 tile, BK=32, THREE-buffer LDS, counted-vmcnt pipeline.
// (round-13 version, verified)
// ---------------------------------------------------------------------------
#define QK_STAGE(buf, kt)                                                       \
    {                                                                           \
        const int k0_ = (kt) << 5;                                              \
        _Pragma("unroll")                                                       \
        for (int i = 0; i < 2; ++i) {                                           \
            const int idx = i * 256 + tid;                                      \
            const int r_ = idx >> 2;                                            \
            const int j_ = idx & 3;                                             \
            const int js_ = j_ ^ ((r_ >> 1) & 3);                               \
            __builtin_amdgcn_global_load_lds(                                   \
                (const __attribute__((address_space(1))) void*)(A + (size_t)(m0 + r_) * K + k0_ + js_ * 8), \
                (__attribute__((address_space(3))) void*)(&As[buf][r_][j_ * 8]), 16, 0, 0); \
        }                                                                       \
        _Pragma("unroll")                                                       \
        for (int i = 0; i < 2; ++i) {                                           \
            const int idx = i * 256 + tid;                                      \
            const int r_ = idx >> 2;                                            \
            const int j_ = idx & 3;                                             \
            const int js_ = j_ ^ ((r_ >> 1) & 3);                               \
            __builtin_amdgcn_global_load_lds(                                   \
                (const __attribute__((address_space(1))) void*)(Bt + (size_t)(n0 + r_) * K + k0_ + js_ * 8), \
                (__attribute__((address_space(3))) void*)(&Bs[buf][r_][j_ * 8]), 16, 0, 0); \
        }                                                                       \
    }

__global__ __launch_bounds__(256, 3) void k_gemm_qkv(
    const __hip_bfloat16* __restrict__ A,
    const __hip_bfloat16* __restrict__ Bt,
    const float* __restrict__ bias,
    int K,
    __hip_bfloat16* __restrict__ Qb,
    __hip_bfloat16* __restrict__ Kb,
    __hip_bfloat16* __restrict__ Vt)
{
    __shared__ __hip_bfloat16 As[3][128][32];
    __shared__ __hip_bfloat16 Bs[3][128][32];

    const int tid = threadIdx.x;
    const int lane = tid & 63;
    const int wid = tid >> 6;
    const int wm = wid >> 1, wn = wid & 1;
    const int m0 = blockIdx.y * 128, n0 = blockIdx.x * 128;
    const int l15 = lane & 15, lg = lane >> 4;
    const int rchunk = (lg ^ ((l15 >> 1) & 3)) * 8;

    f32x4 acc[4][4] = {};
    const int nt = K >> 5;   // 32

    QK_STAGE(0, 0);
    QK_STAGE(1, 1);
    asm volatile("s_waitcnt vmcnt(4)" ::: "memory");
    __builtin_amdgcn_sched_barrier(0);
    __builtin_amdgcn_s_barrier();
    __builtin_amdgcn_sched_barrier(0);

    for (int t = 0; t < nt; ++t) {
        const int cur = t % 3;
        if (t + 2 < nt) {
            const int nxt = (t + 2) % 3;
            QK_STAGE(nxt, t + 2);
        }
        bf16x8 a[4], bb[4];
#pragma unroll
        for (int m = 0; m < 4; ++m)
            a[m] = *(const bf16x8*)&As[cur][wm * 64 + m * 16 + l15][rchunk];
#pragma unroll
        for (int n = 0; n < 4; ++n)
            bb[n] = *(const bf16x8*)&Bs[cur][wn * 64 + n * 16 + l15][rchunk];
        __builtin_amdgcn_s_setprio(1);
#pragma unroll
        for (int m = 0; m < 4; ++m)
#pragma unroll
            for (int n = 0; n < 4; ++n)
                acc[m][n] = __builtin_amdgcn_mfma_f32_16x16x32_bf16(a[m], bb[n], acc[m][n], 0, 0, 0);
        __builtin_amdgcn_s_setprio(0);
        __builtin_amdgcn_sched_barrier(0);
        if (t + 2 < nt)
            asm volatile("s_waitcnt vmcnt(4)" ::: "memory");
        else
            asm volatile("s_waitcnt vmcnt(0)" ::: "memory");
        __builtin_amdgcn_sched_barrier(0);
        __builtin_amdgcn_s_barrier();
        __builtin_amdgcn_sched_barrier(0);
    }

#pragma unroll
    for (int m = 0; m < 4; ++m) {
        const int row = m0 + wm * 64 + m * 16 + lg * 4;
#pragma unroll
        for (int n = 0; n < 4; ++n) {
            const int col = n0 + wn * 64 + n * 16 + l15;
            const float bv = bias[col];
#pragma unroll
            for (int r = 0; r < 4; ++r) {
                const float val = acc[m][n][r] + bv;
                const int rr = row + r;
                const int sec = col >> 10, cw = col & 1023;
                const int hh = cw >> 6, d = cw & 63;
                const int bq = rr >> 11, tt = rr & 2047;
                const int bh = bq * 16 + hh;
                if (sec == 0)
                    Qb[((size_t)bh * 2048 + tt) * 64 + d] = f2b(val * QSCALE);
                else if (sec == 1)
                    Kb[((size_t)bh * 2048 + tt) * 64 + d] = f2b(val);
                else
                    Vt[((size_t)bh * 64 + d) * 2048 + tt] = f2b(val);
            }
        }
    }
}

// ---------------------------------------------------------------------------
// GEMM out: 128x64 tile, BK=32, THREE-buffer counted-vmcnt pipeline.
// (round-15 version, verified)
// ---------------------------------------------------------------------------
#define OUT_STAGE(buf, kt)                                                      \
    {                                                                           \
        const int k0_ = (kt) << 5;                                              \
        _Pragma("unroll")                                                       \
        for (int i = 0; i < 2; ++i) {                                           \
            const int idx = i * 256 + tid;                                      \
            const int r_ = idx >> 2;                                            \
            const int j_ = idx & 3;                                             \
            const int js_ = j_ ^ ((r_ >> 1) & 3);                               \
            __builtin_amdgcn_global_load_lds(                                   \
                (const __attribute__((address_space(1))) void*)(A + (size_t)(m0 + r_) * K + k0_ + js_ * 8), \
                (__attribute__((address_space(3))) void*)(&As[buf][r_][j_ * 8]), 16, 0, 0); \
        }                                                                       \
        {                                                                       \
            const int r_ = tid >> 2;                                            \
            const int j_ = tid & 3;                                             \
            const int js_ = j_ ^ ((r_ >> 1) & 3);                               \
            __builtin_amdgcn_global_load_lds(                                   \
                (const __attribute__((address_space(1))) void*)(Bt + (size_t)(n0 + r_) * K + k0_ + js_ * 8), \
                (__attribute__((address_space(3))) void*)(&Bs[buf][r_][j_ * 8]), 16, 0, 0); \
        }                                                                       \
    }

__global__ __launch_bounds__(256, 4) void k_gemm_out(
    const __hip_bfloat16* __restrict__ A,
    const __hip_bfloat16* __restrict__ Bt,
    const float* __restrict__ bias,
    int K, int Nn,
    float* __restrict__ outf)
{
    __shared__ __hip_bfloat16 As[3][128][32];
    __shared__ __hip_bfloat16 Bs[3][64][32];

    const int tid = threadIdx.x;
    const int lane = tid & 63;
    const int wid = tid >> 6;
    const int wm = wid >> 1, wn = wid & 1;
    const int m0 = blockIdx.y * 128, n0 = blockIdx.x * 64;
    const int l15 = lane & 15, lg = lane >> 4;
    const int rchunk = (lg ^ ((l15 >> 1) & 3)) * 8;

    f32x4 acc[4][2] = {};
    const int nt = K >> 5;   // 32

    OUT_STAGE(0, 0);
    OUT_STAGE(1, 1);
    asm volatile("s_waitcnt vmcnt(3)" ::: "memory");
    __builtin_amdgcn_sched_barrier(0);
    __builtin_amdgcn_s_barrier();
    __builtin_amdgcn_sched_barrier(0);

    for (int t = 0; t < nt; ++t) {
        const int cur = t % 3;
        if (t + 2 < nt) {
            const int nxt = (t + 2) % 3;
            OUT_STAGE(nxt, t + 2);
        }
        bf16x8 a[4], bb[2];
#pragma unroll
        for (int m = 0; m < 4; ++m)
            a[m] = *(const bf16x8*)&As[cur][wm * 64 + m * 16 + l15][rchunk];
#pragma unroll
        for (int n = 0; n < 2; ++n)
            bb[n] = *(const bf16x8*)&Bs[cur][wn * 32 + n * 16 + l15][rchunk];
        __builtin_amdgcn_s_setprio(1);
#pragma unroll
        for (int m = 0; m < 4; ++m)
#pragma unroll
            for (int n = 0; n < 2; ++n)
                acc[m][n] = __builtin_amdgcn_mfma_f32_16x16x32_bf16(a[m], bb[n], acc[m][n], 0, 0, 0);
        __builtin_amdgcn_s_setprio(0);
        __builtin_amdgcn_sched_barrier(0);
        if (t + 2 < nt)
            asm volatile("s_waitcnt vmcnt(3)" ::: "memory");
        else
            asm volatile("s_waitcnt vmcnt(0)" ::: "memory");
        __builtin_amdgcn_sched_barrier(0);
        __builtin_amdgcn_s_barrier();
        __builtin_amdgcn_sched_barrier(0);
    }

#pragma unroll
    for (int m = 0; m < 4; ++m) {
        const int row = m0 + wm * 64 + m * 16 + lg * 4;
#pragma unroll
        for (int n = 0; n < 2; ++n) {
            const int col = n0 + wn * 32 + n * 16 + l15;
            const float bv = bias[col];
#pragma unroll
            for (int r = 0; r < 4; ++r)
                outf[(size_t)(row + r) * Nn + col] = acc[m][n][r] + bv;
        }
    }
}

// ---------------------------------------------------------------------------
// Causal flash attention v14 — round-16 block-shared staging + QK PIPELINE:
// QK^T for tile t+1 is computed at step t (K already LDS-resident), so the
// softmax of tile t never waits on its own QK chain. Two statically-named
// score sets (sA/sB) swap via a double-step loop (NT is always even).
// 3-buffer LDS (64 KB, 2 blocks/CU); vmcnt(0)+barrier per step guarantees
// tile t+2 residency for step t+1's QK. Per-wave math unchanged.
// ---------------------------------------------------------------------------
#define DEFER_THR 4.0f

#define AT_STAGE(buf, tt)                                                       \
    {                                                                           \
        const int ks_ = (tt) << 6;                                              \
        _Pragma("unroll")                                                       \
        for (int i = 0; i < 2; ++i) {                                           \
            const int idx = i * 256 + tid;                                      \
            const int r_ = idx >> 3;                                            \
            const int j_ = idx & 7;                                             \
            const int js_ = j_ ^ (r_ & 7);                                      \
            __builtin_amdgcn_global_load_lds(                                   \
                (const __attribute__((address_space(1))) void*)(Kbase + (size_t)(ks_ + r_) * 64 + js_ * 8), \
                (__attribute__((address_space(3))) void*)(&Ks[buf][r_][j_ * 8]), 16, 0, 0); \
        }                                                                       \
        _Pragma("unroll")                                                       \
        for (int i = 0; i < 2; ++i) {                                           \
            const int idx = i * 256 + tid;                                      \
            const int r_ = idx >> 3;                                            \
            const int j_ = idx & 7;                                             \
            const int js_ = j_ ^ (r_ & 7);                                      \
            __builtin_amdgcn_global_load_lds(                                   \
                (const __attribute__((address_space(1))) void*)(Vbase + (size_t)r_ * 2048 + ks_ + js_ * 8), \
                (__attribute__((address_space(3))) void*)(&Vs[buf][r_][j_ * 8]), 16, 0, 0); \
        }                                                                       \
    }

#define QK_COMP(SN0, SN1, TI)                                                   \
    {                                                                           \
        const int kb_ = (TI) % 3;                                               \
        bf16x8 bk0[4], bk1[4];                                                  \
        _Pragma("unroll")                                                       \
        for (int kf = 0; kf < 4; ++kf) {                                        \
            bk0[kf] = *(const bf16x8*)&Ks[kb_][kf * 16 + l15][(lg ^ kswz) * 8]; \
            bk1[kf] = *(const bf16x8*)&Ks[kb_][kf * 16 + l15][((4 + lg) ^ kswz) * 8]; \
        }                                                                       \
        __builtin_amdgcn_s_setprio(1);                                          \
        _Pragma("unroll")                                                       \
        for (int kf = 0; kf < 4; ++kf) {                                        \
            f32x4 z_ = {};                                                      \
            SN0[kf] = __builtin_amdgcn_mfma_f32_16x16x32_bf16(bk0[kf], aq[0][0], z_, 0, 0, 0); \
            SN0[kf] = __builtin_amdgcn_mfma_f32_16x16x32_bf16(bk1[kf], aq[0][1], SN0[kf], 0, 0, 0); \
            SN1[kf] = __builtin_amdgcn_mfma_f32_16x16x32_bf16(bk0[kf], aq[1][0], z_, 0, 0, 0); \
            SN1[kf] = __builtin_amdgcn_mfma_f32_16x16x32_bf16(bk1[kf], aq[1][1], SN1[kf], 0, 0, 0); \
        }                                                                       \
        __builtin_amdgcn_s_setprio(0);                                          \
    }

#define PROC_FULL(SC0, SC1, TI)                                                 \
    {                                                                           \
        const int vb_ = (TI) % 3;                                               \
        float px0 = fmaxf(fmaxf(fmaxf(SC0[0][0], SC0[0][1]), fmaxf(SC0[0][2], SC0[0][3])), \
                          fmaxf(fmaxf(SC0[1][0], SC0[1][1]), fmaxf(SC0[1][2], SC0[1][3]))); \
        px0 = fmaxf(px0, fmaxf(fmaxf(fmaxf(SC0[2][0], SC0[2][1]), fmaxf(SC0[2][2], SC0[2][3])), \
                               fmaxf(fmaxf(SC0[3][0], SC0[3][1]), fmaxf(SC0[3][2], SC0[3][3])))); \
        float px1 = fmaxf(fmaxf(fmaxf(SC1[0][0], SC1[0][1]), fmaxf(SC1[0][2], SC1[0][3])), \
                          fmaxf(fmaxf(SC1[1][0], SC1[1][1]), fmaxf(SC1[1][2], SC1[1][3]))); \
        px1 = fmaxf(px1, fmaxf(fmaxf(fmaxf(SC1[2][0], SC1[2][1]), fmaxf(SC1[2][2], SC1[2][3])), \
                               fmaxf(fmaxf(SC1[3][0], SC1[3][1]), fmaxf(SC1[3][2], SC1[3][3])))); \
        px0 = fmaxf(px0, __shfl_xor(px0, 16));                                  \
        px0 = fmaxf(px0, __shfl_xor(px0, 32));                                  \
        px1 = fmaxf(px1, __shfl_xor(px1, 16));                                  \
        px1 = fmaxf(px1, __shfl_xor(px1, 32));                                  \
        if (__any((px0 > m0 + DEFER_THR) || (px1 > m1 + DEFER_THR))) {          \
            const float mn0 = fmaxf(m0, px0), mn1 = fmaxf(m1, px1);             \
            const float al0 = exp2fast(m0 - mn0), al1 = exp2fast(m1 - mn1);     \
            m0 = mn0; m1 = mn1;                                                 \
            l0 *= al0; l1 *= al1;                                               \
            _Pragma("unroll")                                                   \
            for (int dc = 0; dc < 4; ++dc)                                      \
                _Pragma("unroll")                                               \
                for (int r = 0; r < 4; ++r) {                                   \
                    o[0][dc][r] *= al0;                                         \
                    o[1][dc][r] *= al1;                                         \
                }                                                               \
        }                                                                       \
        float rs0 = 0.f, rs1 = 0.f;                                             \
        _Pragma("unroll")                                                       \
        for (int kf = 0; kf < 4; ++kf) {                                        \
            _Pragma("unroll")                                                   \
            for (int r = 0; r < 4; ++r) {                                       \
                SC0[kf][r] = exp2fast(SC0[kf][r] - m0);                         \
                SC1[kf][r] = exp2fast(SC1[kf][r] - m1);                         \
                rs0 += SC0[kf][r];                                              \
                rs1 += SC1[kf][r];                                              \
            }                                                                   \
            uint2 w0, w1;                                                       \
            w0.x = pack2(SC0[kf][0], SC0[kf][1]); w0.y = pack2(SC0[kf][2], SC0[kf][3]); \
            w1.x = pack2(SC1[kf][0], SC1[kf][1]); w1.y = pack2(SC1[kf][2], SC1[kf][3]); \
            const int off = l15 * 64 + ((kf * 16 + lg * 4) ^ swz);              \
            *(uint2*)&Pw0[off] = w0;                                            \
            *(uint2*)&Pw1[off] = w1;                                            \
        }                                                                       \
        rs0 += __shfl_xor(rs0, 16); rs0 += __shfl_xor(rs0, 32);                 \
        rs1 += __shfl_xor(rs1, 16); rs1 += __shfl_xor(rs1, 32);                 \
        l0 += rs0; l1 += rs1;                                                   \
        _Pragma("unroll")                                                       \
        for (int c2 = 0; c2 < 2; ++c2) {                                        \
            bf16x8 bv[4];                                                       \
            _Pragma("unroll")                                                   \
            for (int dc = 0; dc < 4; ++dc)                                      \
                bv[dc] = *(const bf16x8*)&Vs[vb_][dc * 16 + l15][(((c2 << 2) | lg) ^ kswz) * 8]; \
            const int off = l15 * 64 + ((c2 * 32 + lg * 8) ^ swz);              \
            const bf16x8 pb0 = *(const bf16x8*)&Pw0[off];                       \
            const bf16x8 pb1 = *(const bf16x8*)&Pw1[off];                       \
            __builtin_amdgcn_s_setprio(1);                                      \
            _Pragma("unroll")                                                   \
            for (int dc = 0; dc < 4; ++dc) {                                    \
                o[0][dc] = __builtin_amdgcn_mfma_f32_16x16x32_bf16(bv[dc], pb0, o[0][dc], 0, 0, 0); \
                o[1][dc] = __builtin_amdgcn_mfma_f32_16x16x32_bf16(bv[dc], pb1, o[1][dc], 0, 0, 0); \
            }                                                                   \
            __builtin_amdgcn_s_setprio(0);                                      \
        }                                                                       \
    }

#define PROC_TAIL_QF(SCX, MV, LV, QF, PWX, VB, KS)                              \
    {                                                                           \
        const int qlo = qw + (QF) * 16;                                         \
        const int qv = qlo + l15;                                               \
        const int kb = (KS) + lg * 4;                                           \
        _Pragma("unroll")                                                       \
        for (int kf = 0; kf < 4; ++kf)                                          \
            _Pragma("unroll")                                                   \
            for (int r = 0; r < 4; ++r)                                         \
                SCX[kf][r] = (kb + kf * 16 + r <= qv) ? SCX[kf][r] : -1e30f;    \
        float mx = fmaxf(fmaxf(fmaxf(SCX[0][0], SCX[0][1]), fmaxf(SCX[0][2], SCX[0][3])), \
                         fmaxf(fmaxf(SCX[1][0], SCX[1][1]), fmaxf(SCX[1][2], SCX[1][3]))); \
        mx = fmaxf(mx, fmaxf(fmaxf(fmaxf(SCX[2][0], SCX[2][1]), fmaxf(SCX[2][2], SCX[2][3])), \
                             fmaxf(fmaxf(SCX[3][0], SCX[3][1]), fmaxf(SCX[3][2], SCX[3][3])))); \
        mx = fmaxf(mx, __shfl_xor(mx, 16));                                     \
        mx = fmaxf(mx, __shfl_xor(mx, 32));                                     \
        const float mnew = fmaxf(MV, mx);                                       \
        const float al = exp2fast(MV - mnew);                                   \
        MV = mnew;                                                              \
        float rs = 0.f;                                                         \
        _Pragma("unroll")                                                       \
        for (int kf = 0; kf < 4; ++kf)                                          \
            _Pragma("unroll")                                                   \
            for (int r = 0; r < 4; ++r) {                                       \
                SCX[kf][r] = exp2fast(SCX[kf][r] - mnew);                       \
                rs += SCX[kf][r];                                               \
            }                                                                   \
        rs += __shfl_xor(rs, 16);                                               \
        rs += __shfl_xor(rs, 32);                                               \
        LV = LV * al + rs;                                                      \
        _Pragma("unroll")                                                       \
        for (int dc = 0; dc < 4; ++dc)                                          \
            _Pragma("unroll")                                                   \
            for (int r = 0; r < 4; ++r) o[QF][dc][r] *= al;                     \
        _Pragma("unroll")                                                       \
        for (int kf = 0; kf < 4; ++kf) {                                        \
            uint2 w;                                                            \
            w.x = pack2(SCX[kf][0], SCX[kf][1]);                                \
            w.y = pack2(SCX[kf][2], SCX[kf][3]);                                \
            *(uint2*)&PWX[l15 * 64 + ((kf * 16 + lg * 4) ^ swz)] = w;           \
        }                                                                       \
        _Pragma("unroll")                                                       \
        for (int c2 = 0; c2 < 2; ++c2) {                                        \
            if ((KS) + c2 * 32 <= qlo + 15) {                                   \
                bf16x8 bv[4];                                                   \
                _Pragma("unroll")                                               \
                for (int dc = 0; dc < 4; ++dc)                                  \
                    bv[dc] = *(const bf16x8*)&Vs[VB][dc * 16 + l15][(((c2 << 2) | lg) ^ kswz) * 8]; \
                const bf16x8 pb = *(const bf16x8*)&PWX[l15 * 64 + ((c2 * 32 + lg * 8) ^ swz)]; \
                _Pragma("unroll")                                               \
                for (int dc = 0; dc < 4; ++dc)                                  \
                    o[QF][dc] = __builtin_amdgcn_mfma_f32_16x16x32_bf16(bv[dc], pb, o[QF][dc], 0, 0, 0); \
            }                                                                   \
        }                                                                       \
    }

#define PROC_TAIL(SC0, SC1, TI)                                                 \
    {                                                                           \
        const int vb_ = (TI) % 3;                                               \
        const int kst_ = nfull * 64;                                            \
        PROC_TAIL_QF(SC0, m0, l0, 0, Pw0, vb_, kst_);                           \
        PROC_TAIL_QF(SC1, m1, l1, 1, Pw1, vb_, kst_);                           \
    }

#define PIPE_STEP(SC0, SC1, SN0, SN1, T)                                        \
    {                                                                           \
        const int t_ = (T);                                                     \
        const int ts_ = (t_ + 2 < NT) ? (t_ + 2) : (NT - 1);                    \
        AT_STAGE((t_ + 2) % 3, ts_);                                            \
        if (t_ + 1 < NT) QK_COMP(SN0, SN1, t_ + 1);                             \
        if (t_ < nfull) {                                                       \
            PROC_FULL(SC0, SC1, t_);                                            \
        } else if (t_ == nfull) {                                               \
            PROC_TAIL(SC0, SC1, t_);                                            \
        }                                                                       \
        __builtin_amdgcn_sched_barrier(0);                                      \
        asm volatile("s_waitcnt vmcnt(0)" ::: "memory");                        \
        __builtin_amdgcn_sched_barrier(0);                                      \
        __builtin_amdgcn_s_barrier();                                           \
        __builtin_amdgcn_sched_barrier(0);                                      \
    }

__global__ __launch_bounds__(256, 2) void k_attn(
    const __hip_bfloat16* __restrict__ Qb,
    const __hip_bfloat16* __restrict__ Kb,
    const __hip_bfloat16* __restrict__ Vt,
    __hip_bfloat16* __restrict__ att)
{
    __shared__ __hip_bfloat16 Ks[3][64][64];          // 24 KB
    __shared__ __hip_bfloat16 Vs[3][64][64];          // 24 KB (row=d, col=key)
    __shared__ __hip_bfloat16 P_lds[4][2][16 * 64];   // 16 KB
    const int tid = threadIdx.x, lane = tid & 63, wid = tid >> 6;
    const int lid = blockIdx.x;
    const int xcd = lid & 7, j = lid >> 3;
    const int jj = j >> 2;
    const int tile = (jj < 8) ? (15 - jj) : (jj - 8);   // heavy tiles first
    const int bh = xcd * 4 + (j & 3);
    const int q0 = tile * 128;
    const int qw = q0 + wid * 32;
    const int l15 = lane & 15, lg = lane >> 4;
    const int swz = (l15 & 7) << 3;
    const int kswz = l15 & 7;

    const __hip_bfloat16* Qbase = Qb + (size_t)bh * 2048 * 64;
    const __hip_bfloat16* Kbase = Kb + (size_t)bh * 2048 * 64;
    const __hip_bfloat16* Vbase = Vt + (size_t)bh * 64 * 2048;

    bf16x8 aq[2][2];
#pragma unroll
    for (int qf = 0; qf < 2; ++qf)
#pragma unroll
        for (int c = 0; c < 2; ++c)
            aq[qf][c] = *(const bf16x8*)(Qbase + (size_t)(qw + qf * 16 + l15) * 64 + c * 32 + lg * 8);

    f32x4 o[2][4] = {};
    float m0 = -1e30f, m1 = -1e30f, l0 = 0.f, l1 = 0.f;

    const int nfull = qw >> 6;          // per-wave full 64-key steps
    const int NT = 2 * tile + 2;        // tiles this block touches (ALWAYS EVEN)
    __hip_bfloat16* Pw0 = &P_lds[wid][0][0];
    __hip_bfloat16* Pw1 = &P_lds[wid][1][0];

    f32x4 sA0[4], sA1[4], sB0[4], sB1[4];

    AT_STAGE(0, 0);
    AT_STAGE(1, 1);                     // keys 64..127 always in-bounds (T=2048)
    asm volatile("s_waitcnt vmcnt(0)" ::: "memory");   // tiles 0,1 landed
    __builtin_amdgcn_sched_barrier(0);
    __builtin_amdgcn_s_barrier();
    __builtin_amdgcn_sched_barrier(0);
    QK_COMP(sA0, sA1, 0);               // scores for tile 0

    for (int tt = 0; tt < NT; tt += 2) {
        PIPE_STEP(sA0, sA1, sB0, sB1, tt);
        PIPE_STEP(sB0, sB1, sA0, sA1, tt + 1);
    }

    const int bq = bh >> 4, hh = bh & 15;
    const float inv0 = 1.0f / l0, inv1 = 1.0f / l1;
#pragma unroll
    for (int qf = 0; qf < 2; ++qf) {
        const float inv = (qf == 0) ? inv0 : inv1;
        const size_t rowb = ((size_t)(bq * 2048 + qw + qf * 16 + l15)) * 1024 + hh * 64;
#pragma unroll
        for (int dc = 0; dc < 4; ++dc) {
            bf16x4 st;
#pragma unroll
            for (int r = 0; r < 4; ++r)
                st[r] = (short)__bfloat16_as_ushort(__float2bfloat16(o[qf][dc][r] * inv));
            *(bf16x4*)(att + rowb + dc * 16 + lg * 4) = st;
        }
    }
}

// ---------------------------------------------------------------------------
extern "C" void kernel_launch(void* const* d_in, const int* in_sizes, int n_in,
                              void* d_out, int out_size, void* d_ws, size_t ws_size,
                              hipStream_t stream)
{
    const float* x    = (const float*)d_in[0];   // [2,2048,1024]
    const float* Wqkv = (const float*)d_in[1];   // [1024,3072]
    const float* bqkv = (const float*)d_in[2];   // [3072]
    const float* Wo   = (const float*)d_in[3];   // [1024,1024]
    const float* bo   = (const float*)d_in[4];   // [1024]
    float* out = (float*)d_out;                  // [2,2048,1024]

    char* ws = (char*)d_ws;
    const size_t MB = 1024 * 1024;
    __hip_bfloat16* xb    = (__hip_bfloat16*)(ws);            //  8 MB
    __hip_bfloat16* WqkvT = (__hip_bfloat16*)(ws + 8 * MB);   //  6 MB
    __hip_bfloat16* WoT   = (__hip_bfloat16*)(ws + 14 * MB);  //  2 MB
    __hip_bfloat16* Qb    = (__hip_bfloat16*)(ws + 16 * MB);  //  8 MB
    __hip_bfloat16* Kb    = (__hip_bfloat16*)(ws + 24 * MB);  //  8 MB
    __hip_bfloat16* Vt    = (__hip_bfloat16*)(ws + 32 * MB);  //  8 MB
    __hip_bfloat16* att   = (__hip_bfloat16*)(ws + 40 * MB);  //  8 MB

    k_prep<<<6144, 256, 0, stream>>>(x, xb, Wqkv, WqkvT, Wo, WoT);

    k_gemm_qkv<<<dim3(24, 32), 256, 0, stream>>>(
        xb, WqkvT, bqkv, 1024, Qb, Kb, Vt);

    k_attn<<<512, 256, 0, stream>>>(Qb, Kb, Vt, att);

    k_gemm_out<<<dim3(16, 32), 256, 0, stream>>>(
        att, WoT, bo, 1024, 1024, out);
}

// Round 20
// 116.137 us; speedup vs baseline: 1.1189x; 1.1189x over previous
//
#include <hip/hip_runtime.h>
#include <hip/hip_bf16.h>

typedef __attribute__((ext_vector_type(8))) short bf16x8;
typedef __attribute__((ext_vector_type(4))) short bf16x4;
typedef __attribute__((ext_vector_type(4))) float f32x4;

static __device__ __forceinline__ __hip_bfloat16 f2b(float f) {
    return __float2bfloat16(f);
}
static __device__ __forceinline__ unsigned pack2(float a, float b) {
    unsigned ua = (unsigned)__bfloat16_as_ushort(__float2bfloat16(a));
    unsigned ub = (unsigned)__bfloat16_as_ushort(__float2bfloat16(b));
    return ua | (ub << 16);
}
static __device__ __forceinline__ float exp2fast(float x) {
    return __builtin_amdgcn_exp2f(x);
}

#define QSCALE 0.1803368801111f   // 0.125 * log2(e)

// ---------------------------------------------------------------------------
// Fused prep: blocks [0,2048) convert x f32->bf16; [2048,5120) transpose
// Wqkv -> WqkvT bf16; [5120,6144) transpose Wo -> WoT bf16.
// ---------------------------------------------------------------------------
__global__ __launch_bounds__(256) void k_prep(
    const float* __restrict__ x, __hip_bfloat16* __restrict__ xb,
    const float* __restrict__ Wqkv, __hip_bfloat16* __restrict__ WqkvT,
    const float* __restrict__ Wo, __hip_bfloat16* __restrict__ WoT)
{
    const int bx = blockIdx.x;
    if (bx < 2048) {
        int i = bx * 256 + threadIdx.x;
        const int stride = 2048 * 256;
        for (; i < 1048576; i += stride) {
            float4 v = reinterpret_cast<const float4*>(x)[i];
            __hip_bfloat16* o = xb + 4 * (size_t)i;
            o[0] = f2b(v.x); o[1] = f2b(v.y); o[2] = f2b(v.z); o[3] = f2b(v.w);
        }
        return;
    }
    __shared__ float tile[32][33];
    const float* in;
    __hip_bfloat16* outp;
    int R, Cn, c0, r0;
    if (bx < 5120) {
        const int b = bx - 2048;
        in = Wqkv; outp = WqkvT; R = 1024; Cn = 3072;
        c0 = (b % 96) * 32; r0 = (b / 96) * 32;
    } else {
        const int b = bx - 5120;
        in = Wo; outp = WoT; R = 1024; Cn = 1024;
        c0 = (b & 31) * 32; r0 = (b >> 5) * 32;
    }
    const int tx = threadIdx.x & 31, ty = threadIdx.x >> 5;
#pragma unroll
    for (int i = 0; i < 32; i += 8)
        tile[ty + i][tx] = in[(size_t)(r0 + ty + i) * Cn + c0 + tx];
    __syncthreads();
#pragma unroll
    for (int i = 0; i < 32; i += 8)
        outp[(size_t)(c0 + ty + i) * R + r0 + tx] = f2b(tile[tx][ty + i]);
}

// ---------------------------------------------------------------------------
// GEMM1 qkv: 128x128 tile, BK=32, THREE-buffer LDS, counted-vmcnt pipeline.
// (round-13 version, verified)
// ---------------------------------------------------------------------------
#define QK_STAGE(buf, kt)                                                       \
    {                                                                           \
        const int k0_ = (kt) << 5;                                              \
        _Pragma("unroll")                                                       \
        for (int i = 0; i < 2; ++i) {                                           \
            const int idx = i * 256 + tid;                                      \
            const int r_ = idx >> 2;                                            \
            const int j_ = idx & 3;                                             \
            const int js_ = j_ ^ ((r_ >> 1) & 3);                               \
            __builtin_amdgcn_global_load_lds(                                   \
                (const __attribute__((address_space(1))) void*)(A + (size_t)(m0 + r_) * K + k0_ + js_ * 8), \
                (__attribute__((address_space(3))) void*)(&As[buf][r_][j_ * 8]), 16, 0, 0); \
        }                                                                       \
        _Pragma("unroll")                                                       \
        for (int i = 0; i < 2; ++i) {                                           \
            const int idx = i * 256 + tid;                                      \
            const int r_ = idx >> 2;                                            \
            const int j_ = idx & 3;                                             \
            const int js_ = j_ ^ ((r_ >> 1) & 3);                               \
            __builtin_amdgcn_global_load_lds(                                   \
                (const __attribute__((address_space(1))) void*)(Bt + (size_t)(n0 + r_) * K + k0_ + js_ * 8), \
                (__attribute__((address_space(3))) void*)(&Bs[buf][r_][j_ * 8]), 16, 0, 0); \
        }                                                                       \
    }

__global__ __launch_bounds__(256, 3) void k_gemm_qkv(
    const __hip_bfloat16* __restrict__ A,
    const __hip_bfloat16* __restrict__ Bt,
    const float* __restrict__ bias,
    int K,
    __hip_bfloat16* __restrict__ Qb,
    __hip_bfloat16* __restrict__ Kb,
    __hip_bfloat16* __restrict__ Vt)
{
    __shared__ __hip_bfloat16 As[3][128][32];
    __shared__ __hip_bfloat16 Bs[3][128][32];

    const int tid = threadIdx.x;
    const int lane = tid & 63;
    const int wid = tid >> 6;
    const int wm = wid >> 1, wn = wid & 1;
    const int m0 = blockIdx.y * 128, n0 = blockIdx.x * 128;
    const int l15 = lane & 15, lg = lane >> 4;
    const int rchunk = (lg ^ ((l15 >> 1) & 3)) * 8;

    f32x4 acc[4][4] = {};
    const int nt = K >> 5;   // 32

    QK_STAGE(0, 0);
    QK_STAGE(1, 1);
    asm volatile("s_waitcnt vmcnt(4)" ::: "memory");
    __builtin_amdgcn_sched_barrier(0);
    __builtin_amdgcn_s_barrier();
    __builtin_amdgcn_sched_barrier(0);

    for (int t = 0; t < nt; ++t) {
        const int cur = t % 3;
        if (t + 2 < nt) {
            const int nxt = (t + 2) % 3;
            QK_STAGE(nxt, t + 2);
        }
        bf16x8 a[4], bb[4];
#pragma unroll
        for (int m = 0; m < 4; ++m)
            a[m] = *(const bf16x8*)&As[cur][wm * 64 + m * 16 + l15][rchunk];
#pragma unroll
        for (int n = 0; n < 4; ++n)
            bb[n] = *(const bf16x8*)&Bs[cur][wn * 64 + n * 16 + l15][rchunk];
        __builtin_amdgcn_s_setprio(1);
#pragma unroll
        for (int m = 0; m < 4; ++m)
#pragma unroll
            for (int n = 0; n < 4; ++n)
                acc[m][n] = __builtin_amdgcn_mfma_f32_16x16x32_bf16(a[m], bb[n], acc[m][n], 0, 0, 0);
        __builtin_amdgcn_s_setprio(0);
        __builtin_amdgcn_sched_barrier(0);
        if (t + 2 < nt)
            asm volatile("s_waitcnt vmcnt(4)" ::: "memory");
        else
            asm volatile("s_waitcnt vmcnt(0)" ::: "memory");
        __builtin_amdgcn_sched_barrier(0);
        __builtin_amdgcn_s_barrier();
        __builtin_amdgcn_sched_barrier(0);
    }

#pragma unroll
    for (int m = 0; m < 4; ++m) {
        const int row = m0 + wm * 64 + m * 16 + lg * 4;
#pragma unroll
        for (int n = 0; n < 4; ++n) {
            const int col = n0 + wn * 64 + n * 16 + l15;
            const float bv = bias[col];
#pragma unroll
            for (int r = 0; r < 4; ++r) {
                const float val = acc[m][n][r] + bv;
                const int rr = row + r;
                const int sec = col >> 10, cw = col & 1023;
                const int hh = cw >> 6, d = cw & 63;
                const int bq = rr >> 11, tt = rr & 2047;
                const int bh = bq * 16 + hh;
                if (sec == 0)
                    Qb[((size_t)bh * 2048 + tt) * 64 + d] = f2b(val * QSCALE);
                else if (sec == 1)
                    Kb[((size_t)bh * 2048 + tt) * 64 + d] = f2b(val);
                else
                    Vt[((size_t)bh * 64 + d) * 2048 + tt] = f2b(val);
            }
        }
    }
}

// ---------------------------------------------------------------------------
// GEMM out: 128x64 tile, BK=32, THREE-buffer counted-vmcnt pipeline.
// (round-15 version, verified)
// ---------------------------------------------------------------------------
#define OUT_STAGE(buf, kt)                                                      \
    {                                                                           \
        const int k0_ = (kt) << 5;                                              \
        _Pragma("unroll")                                                       \
        for (int i = 0; i < 2; ++i) {                                           \
            const int idx = i * 256 + tid;                                      \
            const int r_ = idx >> 2;                                            \
            const int j_ = idx & 3;                                             \
            const int js_ = j_ ^ ((r_ >> 1) & 3);                               \
            __builtin_amdgcn_global_load_lds(                                   \
                (const __attribute__((address_space(1))) void*)(A + (size_t)(m0 + r_) * K + k0_ + js_ * 8), \
                (__attribute__((address_space(3))) void*)(&As[buf][r_][j_ * 8]), 16, 0, 0); \
        }                                                                       \
        {                                                                       \
            const int r_ = tid >> 2;                                            \
            const int j_ = tid & 3;                                             \
            const int js_ = j_ ^ ((r_ >> 1) & 3);                               \
            __builtin_amdgcn_global_load_lds(                                   \
                (const __attribute__((address_space(1))) void*)(Bt + (size_t)(n0 + r_) * K + k0_ + js_ * 8), \
                (__attribute__((address_space(3))) void*)(&Bs[buf][r_][j_ * 8]), 16, 0, 0); \
        }                                                                       \
    }

__global__ __launch_bounds__(256, 4) void k_gemm_out(
    const __hip_bfloat16* __restrict__ A,
    const __hip_bfloat16* __restrict__ Bt,
    const float* __restrict__ bias,
    int K, int Nn,
    float* __restrict__ outf)
{
    __shared__ __hip_bfloat16 As[3][128][32];
    __shared__ __hip_bfloat16 Bs[3][64][32];

    const int tid = threadIdx.x;
    const int lane = tid & 63;
    const int wid = tid >> 6;
    const int wm = wid >> 1, wn = wid & 1;
    const int m0 = blockIdx.y * 128, n0 = blockIdx.x * 64;
    const int l15 = lane & 15, lg = lane >> 4;
    const int rchunk = (lg ^ ((l15 >> 1) & 3)) * 8;

    f32x4 acc[4][2] = {};
    const int nt = K >> 5;   // 32

    OUT_STAGE(0, 0);
    OUT_STAGE(1, 1);
    asm volatile("s_waitcnt vmcnt(3)" ::: "memory");
    __builtin_amdgcn_sched_barrier(0);
    __builtin_amdgcn_s_barrier();
    __builtin_amdgcn_sched_barrier(0);

    for (int t = 0; t < nt; ++t) {
        const int cur = t % 3;
        if (t + 2 < nt) {
            const int nxt = (t + 2) % 3;
            OUT_STAGE(nxt, t + 2);
        }
        bf16x8 a[4], bb[2];
#pragma unroll
        for (int m = 0; m < 4; ++m)
            a[m] = *(const bf16x8*)&As[cur][wm * 64 + m * 16 + l15][rchunk];
#pragma unroll
        for (int n = 0; n < 2; ++n)
            bb[n] = *(const bf16x8*)&Bs[cur][wn * 32 + n * 16 + l15][rchunk];
        __builtin_amdgcn_s_setprio(1);
#pragma unroll
        for (int m = 0; m < 4; ++m)
#pragma unroll
            for (int n = 0; n < 2; ++n)
                acc[m][n] = __builtin_amdgcn_mfma_f32_16x16x32_bf16(a[m], bb[n], acc[m][n], 0, 0, 0);
        __builtin_amdgcn_s_setprio(0);
        __builtin_amdgcn_sched_barrier(0);
        if (t + 2 < nt)
            asm volatile("s_waitcnt vmcnt(3)" ::: "memory");
        else
            asm volatile("s_waitcnt vmcnt(0)" ::: "memory");
        __builtin_amdgcn_sched_barrier(0);
        __builtin_amdgcn_s_barrier();
        __builtin_amdgcn_sched_barrier(0);
    }

#pragma unroll
    for (int m = 0; m < 4; ++m) {
        const int row = m0 + wm * 64 + m * 16 + lg * 4;
#pragma unroll
        for (int n = 0; n < 2; ++n) {
            const int col = n0 + wn * 32 + n * 16 + l15;
            const float bv = bias[col];
#pragma unroll
            for (int r = 0; r < 4; ++r)
                outf[(size_t)(row + r) * Nn + col] = acc[m][n][r] + bv;
        }
    }
}

// ---------------------------------------------------------------------------
// Causal flash attention v15 — round-16 block-shared staging with 16 q-rows
// per wave (single qf): 1024 blocks x 4 waves over 64-row q-tiles.
// LDS 40 KB -> 4 blocks/CU (160 KB exact) = 16 waves/CU, 2x round-16 TLP.
// launch_bounds(256,4); per-wave regs ~70 (no K-dbuf, single score set).
// Staging/softmax machinery identical to round 16 (verified 57 us).
// ---------------------------------------------------------------------------
#define DEFER_THR 4.0f

#define AT_STAGE(buf, tt)                                                       \
    {                                                                           \
        const int ks_ = (tt) << 6;                                              \
        _Pragma("unroll")                                                       \
        for (int i = 0; i < 2; ++i) {                                           \
            const int idx = i * 256 + tid;                                      \
            const int r_ = idx >> 3;                                            \
            const int j_ = idx & 7;                                             \
            const int js_ = j_ ^ (r_ & 7);                                      \
            __builtin_amdgcn_global_load_lds(                                   \
                (const __attribute__((address_space(1))) void*)(Kbase + (size_t)(ks_ + r_) * 64 + js_ * 8), \
                (__attribute__((address_space(3))) void*)(&Ks[buf][r_][j_ * 8]), 16, 0, 0); \
        }                                                                       \
        _Pragma("unroll")                                                       \
        for (int i = 0; i < 2; ++i) {                                           \
            const int idx = i * 256 + tid;                                      \
            const int r_ = idx >> 3;                                            \
            const int j_ = idx & 7;                                             \
            const int js_ = j_ ^ (r_ & 7);                                      \
            __builtin_amdgcn_global_load_lds(                                   \
                (const __attribute__((address_space(1))) void*)(Vbase + (size_t)r_ * 2048 + ks_ + js_ * 8), \
                (__attribute__((address_space(3))) void*)(&Vs[buf][r_][j_ * 8]), 16, 0, 0); \
        }                                                                       \
    }

#define FULL_STEP_L(BUF)                                                        \
    {                                                                           \
        bf16x8 bk0[4], bk1[4];                                                  \
        _Pragma("unroll")                                                       \
        for (int kf = 0; kf < 4; ++kf) {                                        \
            bk0[kf] = *(const bf16x8*)&Ks[BUF][kf * 16 + l15][(lg ^ kswz) * 8]; \
            bk1[kf] = *(const bf16x8*)&Ks[BUF][kf * 16 + l15][((4 + lg) ^ kswz) * 8]; \
        }                                                                       \
        f32x4 s[4] = {};                                                        \
        __builtin_amdgcn_s_setprio(1);                                          \
        _Pragma("unroll")                                                       \
        for (int kf = 0; kf < 4; ++kf) {                                        \
            s[kf] = __builtin_amdgcn_mfma_f32_16x16x32_bf16(bk0[kf], aq0, s[kf], 0, 0, 0); \
            s[kf] = __builtin_amdgcn_mfma_f32_16x16x32_bf16(bk1[kf], aq1, s[kf], 0, 0, 0); \
        }                                                                       \
        __builtin_amdgcn_s_setprio(0);                                          \
        float px = fmaxf(fmaxf(fmaxf(s[0][0], s[0][1]), fmaxf(s[0][2], s[0][3])), \
                         fmaxf(fmaxf(s[1][0], s[1][1]), fmaxf(s[1][2], s[1][3]))); \
        px = fmaxf(px, fmaxf(fmaxf(fmaxf(s[2][0], s[2][1]), fmaxf(s[2][2], s[2][3])), \
                             fmaxf(fmaxf(s[3][0], s[3][1]), fmaxf(s[3][2], s[3][3])))); \
        px = fmaxf(px, __shfl_xor(px, 16));                                     \
        px = fmaxf(px, __shfl_xor(px, 32));                                     \
        if (__any(px > m0 + DEFER_THR)) {                                       \
            const float mn_ = fmaxf(m0, px);                                    \
            const float al_ = exp2fast(m0 - mn_);                               \
            m0 = mn_; l0 *= al_;                                                \
            _Pragma("unroll")                                                   \
            for (int dc = 0; dc < 4; ++dc)                                      \
                _Pragma("unroll")                                               \
                for (int r = 0; r < 4; ++r) o[dc][r] *= al_;                    \
        }                                                                       \
        float rs_ = 0.f;                                                        \
        _Pragma("unroll")                                                       \
        for (int kf = 0; kf < 4; ++kf) {                                        \
            _Pragma("unroll")                                                   \
            for (int r = 0; r < 4; ++r) {                                       \
                s[kf][r] = exp2fast(s[kf][r] - m0);                             \
                rs_ += s[kf][r];                                                \
            }                                                                   \
            uint2 w_;                                                           \
            w_.x = pack2(s[kf][0], s[kf][1]);                                   \
            w_.y = pack2(s[kf][2], s[kf][3]);                                   \
            *(uint2*)&Pw[l15 * 64 + ((kf * 16 + lg * 4) ^ swz)] = w_;           \
        }                                                                       \
        rs_ += __shfl_xor(rs_, 16);                                             \
        rs_ += __shfl_xor(rs_, 32);                                             \
        l0 += rs_;                                                              \
        _Pragma("unroll")                                                       \
        for (int c2 = 0; c2 < 2; ++c2) {                                        \
            bf16x8 bv[4];                                                       \
            _Pragma("unroll")                                                   \
            for (int dc = 0; dc < 4; ++dc)                                      \
                bv[dc] = *(const bf16x8*)&Vs[BUF][dc * 16 + l15][(((c2 << 2) | lg) ^ kswz) * 8]; \
            const bf16x8 pb = *(const bf16x8*)&Pw[l15 * 64 + ((c2 * 32 + lg * 8) ^ swz)]; \
            __builtin_amdgcn_s_setprio(1);                                      \
            _Pragma("unroll")                                                   \
            for (int dc = 0; dc < 4; ++dc)                                      \
                o[dc] = __builtin_amdgcn_mfma_f32_16x16x32_bf16(bv[dc], pb, o[dc], 0, 0, 0); \
            __builtin_amdgcn_s_setprio(0);                                      \
        }                                                                       \
    }

#define TAIL_STEP_L(BUF)                                                        \
    {                                                                           \
        const int ks_ = nfull * 64;                                             \
        const int qv = qw + l15;                                                \
        bf16x8 bk0[4], bk1[4];                                                  \
        _Pragma("unroll")                                                       \
        for (int kf = 0; kf < 4; ++kf) {                                        \
            bk0[kf] = *(const bf16x8*)&Ks[BUF][kf * 16 + l15][(lg ^ kswz) * 8]; \
            bk1[kf] = *(const bf16x8*)&Ks[BUF][kf * 16 + l15][((4 + lg) ^ kswz) * 8]; \
        }                                                                       \
        f32x4 s[4] = {};                                                        \
        _Pragma("unroll")                                                       \
        for (int kf = 0; kf < 4; ++kf) {                                        \
            if (ks_ + kf * 16 <= qw + 15) {                                     \
                s[kf] = __builtin_amdgcn_mfma_f32_16x16x32_bf16(bk0[kf], aq0, s[kf], 0, 0, 0); \
                s[kf] = __builtin_amdgcn_mfma_f32_16x16x32_bf16(bk1[kf], aq1, s[kf], 0, 0, 0); \
            }                                                                   \
        }                                                                       \
        const int kb = ks_ + lg * 4;                                            \
        _Pragma("unroll")                                                       \
        for (int kf = 0; kf < 4; ++kf)                                          \
            _Pragma("unroll")                                                   \
            for (int r = 0; r < 4; ++r)                                         \
                s[kf][r] = (kb + kf * 16 + r <= qv) ? s[kf][r] : -1e30f;        \
        float mx = fmaxf(fmaxf(fmaxf(s[0][0], s[0][1]), fmaxf(s[0][2], s[0][3])), \
                         fmaxf(fmaxf(s[1][0], s[1][1]), fmaxf(s[1][2], s[1][3]))); \
        mx = fmaxf(mx, fmaxf(fmaxf(fmaxf(s[2][0], s[2][1]), fmaxf(s[2][2], s[2][3])), \
                             fmaxf(fmaxf(s[3][0], s[3][1]), fmaxf(s[3][2], s[3][3])))); \
        mx = fmaxf(mx, __shfl_xor(mx, 16));                                     \
        mx = fmaxf(mx, __shfl_xor(mx, 32));                                     \
        const float mnew = fmaxf(m0, mx);                                       \
        const float al_ = exp2fast(m0 - mnew);                                  \
        m0 = mnew;                                                              \
        float rs_ = 0.f;                                                        \
        _Pragma("unroll")                                                       \
        for (int kf = 0; kf < 4; ++kf)                                          \
            _Pragma("unroll")                                                   \
            for (int r = 0; r < 4; ++r) {                                       \
                s[kf][r] = exp2fast(s[kf][r] - mnew);                           \
                rs_ += s[kf][r];                                                \
            }                                                                   \
        rs_ += __shfl_xor(rs_, 16);                                             \
        rs_ += __shfl_xor(rs_, 32);                                             \
        l0 = l0 * al_ + rs_;                                                    \
        _Pragma("unroll")                                                       \
        for (int dc = 0; dc < 4; ++dc)                                          \
            _Pragma("unroll")                                                   \
            for (int r = 0; r < 4; ++r) o[dc][r] *= al_;                        \
        _Pragma("unroll")                                                       \
        for (int kf = 0; kf < 4; ++kf) {                                        \
            uint2 w_;                                                           \
            w_.x = pack2(s[kf][0], s[kf][1]);                                   \
            w_.y = pack2(s[kf][2], s[kf][3]);                                   \
            *(uint2*)&Pw[l15 * 64 + ((kf * 16 + lg * 4) ^ swz)] = w_;           \
        }                                                                       \
        _Pragma("unroll")                                                       \
        for (int c2 = 0; c2 < 2; ++c2) {                                        \
            if (ks_ + c2 * 32 <= qw + 15) {                                     \
                bf16x8 bv[4];                                                   \
                _Pragma("unroll")                                               \
                for (int dc = 0; dc < 4; ++dc)                                  \
                    bv[dc] = *(const bf16x8*)&Vs[BUF][dc * 16 + l15][(((c2 << 2) | lg) ^ kswz) * 8]; \
                const bf16x8 pb = *(const bf16x8*)&Pw[l15 * 64 + ((c2 * 32 + lg * 8) ^ swz)]; \
                _Pragma("unroll")                                               \
                for (int dc = 0; dc < 4; ++dc)                                  \
                    o[dc] = __builtin_amdgcn_mfma_f32_16x16x32_bf16(bv[dc], pb, o[dc], 0, 0, 0); \
            }                                                                   \
        }                                                                       \
    }

__global__ __launch_bounds__(256, 4) void k_attn(
    const __hip_bfloat16* __restrict__ Qb,
    const __hip_bfloat16* __restrict__ Kb,
    const __hip_bfloat16* __restrict__ Vt,
    __hip_bfloat16* __restrict__ att)
{
    __shared__ __hip_bfloat16 Ks[2][64][64];          // 16 KB
    __shared__ __hip_bfloat16 Vs[2][64][64];          // 16 KB (row=d, col=key)
    __shared__ __hip_bfloat16 P_lds[4][16 * 64];      //  8 KB
    const int tid = threadIdx.x, lane = tid & 63, wid = tid >> 6;
    const int lid = blockIdx.x;                  // 0..1023
    const int xcd = lid & 7, j = lid >> 3;       // j 0..127
    const int bh = xcd * 4 + (j & 3);            // 4 heads per XCD
    const int v = j >> 2;                        // 0..31
    // complementary tile map: per-CU slot-set sums constant
    const int tile = (v < 8) ? (31 - v) : ((v < 16) ? (v - 8) : ((v < 24) ? (39 - v) : (v - 16)));
    const int q0 = tile * 64;
    const int qw = q0 + wid * 16;
    const int l15 = lane & 15, lg = lane >> 4;
    const int swz = (l15 & 7) << 3;
    const int kswz = l15 & 7;

    const __hip_bfloat16* Qbase = Qb + (size_t)bh * 2048 * 64;
    const __hip_bfloat16* Kbase = Kb + (size_t)bh * 2048 * 64;
    const __hip_bfloat16* Vbase = Vt + (size_t)bh * 64 * 2048;

    const bf16x8 aq0 = *(const bf16x8*)(Qbase + (size_t)(qw + l15) * 64 + lg * 8);
    const bf16x8 aq1 = *(const bf16x8*)(Qbase + (size_t)(qw + l15) * 64 + 32 + lg * 8);

    f32x4 o[4] = {};
    float m0 = -1e30f, l0 = 0.f;

    const int nfull = qw >> 6;          // == tile for all waves (wid*16 < 64)
    const int NT = tile + 1;            // tiles this block touches
    __hip_bfloat16* Pw = &P_lds[wid][0];

    AT_STAGE(0, 0);
    __syncthreads();                    // tile 0 resident

    int cur = 0;
    for (int tt = 0; tt < NT; ++tt) {
        if (tt + 1 < NT) AT_STAGE(cur ^ 1, tt + 1);   // prefetch in flight
        if (tt < nfull) {
            FULL_STEP_L(cur);
        } else {
            TAIL_STEP_L(cur);
        }
        __syncthreads();                // drains stage + protects reuse
        cur ^= 1;
    }

    const int bq = bh >> 4, hh = bh & 15;
    const float inv = 1.0f / l0;
    const size_t rowb = ((size_t)(bq * 2048 + qw + l15)) * 1024 + hh * 64;
#pragma unroll
    for (int dc = 0; dc < 4; ++dc) {
        bf16x4 st;
#pragma unroll
        for (int r = 0; r < 4; ++r)
            st[r] = (short)__bfloat16_as_ushort(__float2bfloat16(o[dc][r] * inv));
        *(bf16x4*)(att + rowb + dc * 16 + lg * 4) = st;
    }
}

// ---------------------------------------------------------------------------
extern "C" void kernel_launch(void* const* d_in, const int* in_sizes, int n_in,
                              void* d_out, int out_size, void* d_ws, size_t ws_size,
                              hipStream_t stream)
{
    const float* x    = (const float*)d_in[0];   // [2,2048,1024]
    const float* Wqkv = (const float*)d_in[1];   // [1024,3072]
    const float* bqkv = (const float*)d_in[2];   // [3072]
    const float* Wo   = (const float*)d_in[3];   // [1024,1024]
    const float* bo   = (const float*)d_in[4];   // [1024]
    float* out = (float*)d_out;                  // [2,2048,1024]

    char* ws = (char*)d_ws;
    const size_t MB = 1024 * 1024;
    __hip_bfloat16* xb    = (__hip_bfloat16*)(ws);            //  8 MB
    __hip_bfloat16* WqkvT = (__hip_bfloat16*)(ws + 8 * MB);   //  6 MB
    __hip_bfloat16* WoT   = (__hip_bfloat16*)(ws + 14 * MB);  //  2 MB
    __hip_bfloat16* Qb    = (__hip_bfloat16*)(ws + 16 * MB);  //  8 MB
    __hip_bfloat16* Kb    = (__hip_bfloat16*)(ws + 24 * MB);  //  8 MB
    __hip_bfloat16* Vt    = (__hip_bfloat16*)(ws + 32 * MB);  //  8 MB
    __hip_bfloat16* att   = (__hip_bfloat16*)(ws + 40 * MB);  //  8 MB

    k_prep<<<6144, 256, 0, stream>>>(x, xb, Wqkv, WqkvT, Wo, WoT);

    k_gemm_qkv<<<dim3(24, 32), 256, 0, stream>>>(
        xb, WqkvT, bqkv, 1024, Qb, Kb, Vt);

    k_attn<<<1024, 256, 0, stream>>>(Qb, Kb, Vt, att);

    k_gemm_out<<<dim3(16, 32), 256, 0, stream>>>(
        att, WoT, bo, 1024, 1024, out);
}